// Round 3
// baseline (12084.185 us; speedup 1.0000x reference)
//
#include <hip/hip_runtime.h>
#include <hip/hip_fp16.h>

typedef _Float16 f16;
typedef __attribute__((ext_vector_type(8))) _Float16 f16x8;
typedef __attribute__((ext_vector_type(4))) float f32x4;

// ---------------------------------------------------------------------------
// Direct-load 128x128 tile GEMM (no LDS, no syncthreads in K-loop).
// C[128 m x 128 n] = A[128 x K] @ B(rows)[128 x K]^T
// A row-major (lda); B row-major (ldb), tile n-col t*16+l15 -> B row
//   nbase + g*strideG + j*16 + l15   where t = g*2 + j.
// 8 waves: mq = w&3 (32 m-rows), j = w>>2 (16-col half per gate group).
// Each lane loads its MFMA fragments directly: 16B/lane, 64B contiguous per
// 4 quads -> full cache lines. acc[mt][g]: m = mq*32+mt*16+quad*4+reg,
// n-col-in-tile = l15, gate/group g. Fence-free s_barrier every 8 iters
// keeps waves time-aligned so L1 (32KB) dedups cross-wave fragment reads.
// ---------------------------------------------------------------------------
__device__ __forceinline__ void gemm_direct(
    const f16* __restrict__ A, int lda,
    const f16* __restrict__ Bm, int ldb,
    int K, int bm0, int nbase, int strideG,
    f32x4 acc[2][4])
{
    const int tid  = threadIdx.x;
    const int w    = tid >> 6;
    const int lane = tid & 63;
    const int l15  = lane & 15;
    const int quad = lane >> 4;
    const int mq   = w & 3;
    const int j    = w >> 2;

    #pragma unroll
    for (int mt = 0; mt < 2; ++mt)
      #pragma unroll
      for (int g = 0; g < 4; ++g)
        acc[mt][g] = (f32x4){0.f, 0.f, 0.f, 0.f};

    const f16* pA[2];
    #pragma unroll
    for (int mt = 0; mt < 2; ++mt)
        pA[mt] = A + (size_t)(bm0 + mq * 32 + mt * 16 + l15) * lda + quad * 8;
    const f16* pB[4];
    #pragma unroll
    for (int g = 0; g < 4; ++g)
        pB[g] = Bm + (size_t)(nbase + g * strideG + j * 16 + l15) * ldb + quad * 8;

    for (int k0 = 0; k0 < K; k0 += 32) {
        f16x8 af[2], bf[4];
        #pragma unroll
        for (int mt = 0; mt < 2; ++mt)
            af[mt] = *(const f16x8*)(pA[mt] + k0);
        #pragma unroll
        for (int g = 0; g < 4; ++g)
            bf[g] = *(const f16x8*)(pB[g] + k0);
        #pragma unroll
        for (int mt = 0; mt < 2; ++mt)
          #pragma unroll
          for (int g = 0; g < 4; ++g)
            acc[mt][g] = __builtin_amdgcn_mfma_f32_16x16x32_f16(
                af[mt], bf[g], acc[mt][g], 0, 0, 0);
        if ((k0 & 255) == 224) __builtin_amdgcn_s_barrier();  // raw, no fence
    }
}

// ---------------------------------------------------------------------------
// One recurrent step (also step 0 with A=x0,K=128,W=W_ih):
// gates = A @ W^T + bias ; cell ; write h (f16) and c (fp32).
// Block: 128 batch x (32 hid x 4 gates); g == gate index -> cell in-lane.
// XCD swizzle pins each XCD to a 4MB W'-band (its L2 size).
// ---------------------------------------------------------------------------
__global__ __launch_bounds__(512, 2) void k_step(
    const f16* __restrict__ A, int lda, int K,
    const f16* __restrict__ W, int ldb,
    const float* __restrict__ bias,
    float* __restrict__ Cst,
    f16* __restrict__ Hout)
{
    const int blk = blockIdx.x;
    const int ng  = (blk & 7) * 8 + ((blk >> 3) & 7);  // 0..63, xcd-pinned
    const int bg  = blk >> 6;                           // 0..3
    const int hid0 = ng * 32;
    const int bm0  = bg * 128;
    f32x4 acc[2][4];
    gemm_direct(A, lda, W, ldb, K, bm0, hid0, 2048, acc);

    const int w = threadIdx.x >> 6;
    const int lane = threadIdx.x & 63;
    const int l15 = lane & 15, quad = lane >> 4;
    const int mq = w & 3, j = w >> 2;
    const int hid = hid0 + j * 16 + l15;
    const float bI = bias[hid];
    const float bF = bias[2048 + hid];
    const float bG = bias[4096 + hid];
    const float bO = bias[6144 + hid];
    #pragma unroll
    for (int mt = 0; mt < 2; ++mt) {
      #pragma unroll
      for (int reg = 0; reg < 4; ++reg) {
        const int row = bm0 + mq * 32 + mt * 16 + quad * 4 + reg;
        const size_t idx = (size_t)row * 2048 + hid;
        float iv = acc[mt][0][reg] + bI;
        float fv = acc[mt][1][reg] + bF;
        float gv = acc[mt][2][reg] + bG;
        float ov = acc[mt][3][reg] + bO;
        float si = 1.f / (1.f + __expf(-iv));
        float sf = 1.f / (1.f + __expf(-fv));
        float so = 1.f / (1.f + __expf(-ov));
        float tg = tanhf(gv);
        float c = sf * Cst[idx] + si * tg;
        Cst[idx] = c;
        Hout[idx] = (f16)(so * tanhf(c));
      }
    }
}

// out[b, t, d] = H[slot, b, :] @ W_out[d, :] + b_out[d];  t = t0 + slot
__global__ __launch_bounds__(512, 2) void k_out(
    const f16* __restrict__ Hbase,
    const f16* __restrict__ Wout,
    const float* __restrict__ bout,
    float* __restrict__ out, int t0)
{
    const int bm0 = blockIdx.x * 128;  // over M = depth*512
    f32x4 acc[2][4];
    gemm_direct(Hbase, 2048, Wout, 2048, 2048, bm0, 0, 32, acc);
    const int w = threadIdx.x >> 6;
    const int lane = threadIdx.x & 63;
    const int l15 = lane & 15, quad = lane >> 4;
    const int mq = w & 3, j = w >> 2;
    #pragma unroll
    for (int g = 0; g < 4; ++g) {
      const int d = g * 32 + j * 16 + l15;
      const float bo = bout[d];
      #pragma unroll
      for (int mt = 0; mt < 2; ++mt) {
        #pragma unroll
        for (int reg = 0; reg < 4; ++reg) {
          const int m = bm0 + mq * 32 + mt * 16 + quad * 4 + reg;
          const int slot = m >> 9, b = m & 511;
          const int t = t0 + slot;
          out[(size_t)b * 16384 + t * 128 + d] = acc[mt][g][reg] + bo;
        }
      }
    }
}

// W'[r,k] = W_hh[r,k] + sum_d W_ih[r,d]*W_out[d,k]; MFMA + LDS-coalesced
// epilogue (acc roundtrip through LDS -> dwordx4 Whh reads, 16B Wc stores).
__global__ __launch_bounds__(512, 2) void k_wcomb2(
    const f16* __restrict__ Wih16, const f16* __restrict__ WoutT,
    const float* __restrict__ Whh, f16* __restrict__ Wc)
{
    __shared__ float T[32 * 132];
    const int n0  = blockIdx.x * 128;  // 16 blocks over 2048 cols
    const int bm0 = blockIdx.y * 128;  // 64 blocks over 8192 rows
    f32x4 acc[2][4];
    gemm_direct(Wih16, 128, WoutT, 128, 128, bm0, n0, 32, acc);
    const int tid = threadIdx.x;
    const int w = tid >> 6;
    const int lane = tid & 63;
    const int l15 = lane & 15, quad = lane >> 4;
    const int mq = w & 3, j = w >> 2;
    const int lrow = tid >> 4, lcb = (tid & 15) * 8;
    for (int c = 0; c < 4; ++c) {
        if (mq == c) {
            #pragma unroll
            for (int mt = 0; mt < 2; ++mt)
              #pragma unroll
              for (int g = 0; g < 4; ++g)
                #pragma unroll
                for (int reg = 0; reg < 4; ++reg)
                    T[(mt * 16 + quad * 4 + reg) * 132 + (g * 2 + j) * 16 + l15]
                        = acc[mt][g][reg];
        }
        __syncthreads();
        const int grow = bm0 + c * 32 + lrow;
        const float* wp = Whh + (size_t)grow * 2048 + n0 + lcb;
        f16x8 o;
        #pragma unroll
        for (int u = 0; u < 8; ++u)
            o[u] = (f16)(T[lrow * 132 + lcb + u] + wp[u]);
        *(f16x8*)(Wc + (size_t)grow * 2048 + n0 + lcb) = o;
        __syncthreads();
    }
}

// ---------------- prep kernels (run once per launch) ------------------------

__global__ void k_cast(const float* __restrict__ s, f16* __restrict__ d, int n)
{
    int i = blockIdx.x * 256 + threadIdx.x;
    if (i < n) d[i] = (f16)s[i];
}

// WoutT[k,d] = Wout[d,k]  (fp32 [128 x 2048] -> f16 [2048 x 128])
__global__ __launch_bounds__(256) void k_tr(const float* __restrict__ Wout,
                                            f16* __restrict__ WoutT)
{
    __shared__ float T[64][65];
    const int k0 = blockIdx.x * 64;  // 32
    const int d0 = blockIdx.y * 64;  // 2
    const int t = threadIdx.x;
    const int r = t >> 2, cq = t & 3;
    #pragma unroll
    for (int jj = 0; jj < 4; ++jj) {
        const float* p = Wout + (size_t)(d0 + r) * 2048 + k0 + cq * 16 + jj * 4;
        T[r][cq * 16 + jj * 4 + 0] = p[0];
        T[r][cq * 16 + jj * 4 + 1] = p[1];
        T[r][cq * 16 + jj * 4 + 2] = p[2];
        T[r][cq * 16 + jj * 4 + 3] = p[3];
    }
    __syncthreads();
    f16 tmp[16];
    #pragma unroll
    for (int jj = 0; jj < 16; ++jj) tmp[jj] = (f16)T[cq * 16 + jj][r];
    #pragma unroll
    for (int jj = 0; jj < 16; ++jj)
        WoutT[(size_t)(k0 + r) * 128 + d0 + cq * 16 + jj] = tmp[jj];
}

__global__ void k_x0(const float* __restrict__ tgt, f16* __restrict__ x0)
{
    int i = blockIdx.x * 256 + threadIdx.x;  // 65536 total
    int b = i >> 7, d = i & 127;
    x0[i] = (f16)tgt[(size_t)b * 16384 + d];  // tgt[b, 0, d]
}

__global__ void k_bias(const float* __restrict__ bih, const float* __restrict__ bhh,
                       const float* __restrict__ Wih, const float* __restrict__ bout,
                       float* __restrict__ b0, float* __restrict__ bp)
{
    int r = blockIdx.x * 256 + threadIdx.x;
    if (r >= 8192) return;
    float s = bih[r] + bhh[r];
    float a = 0.f;
    for (int d = 0; d < 128; ++d) a += Wih[(size_t)r * 128 + d] * bout[d];
    b0[r] = s;        // step-0 bias
    bp[r] = s + a;    // recurrent bias (absorbs W_ih @ b_out)
}

// ---------------------------------------------------------------------------

extern "C" void kernel_launch(void* const* d_in, const int* in_sizes, int n_in,
                              void* d_out, int out_size, void* d_ws, size_t ws_size,
                              hipStream_t stream)
{
    const float* tgt  = (const float*)d_in[0];
    const float* Wih  = (const float*)d_in[1];
    const float* Whh  = (const float*)d_in[2];
    const float* bih  = (const float*)d_in[3];
    const float* bhh  = (const float*)d_in[4];
    const float* Wout = (const float*)d_in[5];
    const float* bout = (const float*)d_in[6];
    float* out = (float*)d_out;

    char* ws = (char*)d_ws;
    size_t off = 0;
    auto alloc = [&](size_t bytes) -> void* {
        void* p = ws + off;
        off += (bytes + 255) & ~(size_t)255;
        return p;
    };
    f16*   Wc     = (f16*)alloc((size_t)8192 * 2048 * 2);  // W_hh + W_ih*W_out
    f16*   Wih16  = (f16*)alloc((size_t)8192 * 128 * 2);
    f16*   Wout16 = (f16*)alloc((size_t)128 * 2048 * 2);
    f16*   WoutT  = (f16*)alloc((size_t)2048 * 128 * 2);
    f16*   x0     = (f16*)alloc((size_t)512 * 128 * 2);
    float* b0     = (float*)alloc(8192 * 4);
    float* bp     = (float*)alloc(8192 * 4);
    float* Cst    = (float*)alloc((size_t)512 * 2048 * 4);

    const size_t slotsz = (size_t)512 * 2048;  // elements per h snapshot
    int depth = 0;
    const int cands[7] = {128, 64, 32, 16, 8, 4, 2};
    for (int i = 0; i < 7; ++i)
        if (off + (size_t)cands[i] * slotsz * 2 <= ws_size) { depth = cands[i]; break; }
    if (depth == 0) return;
    f16* Hbuf = (f16*)alloc((size_t)depth * slotsz * 2);

    hipMemsetAsync(Cst, 0, (size_t)512 * 2048 * 4, stream);
    k_cast<<<dim3(4096), dim3(256), 0, stream>>>(Wih, Wih16, 1048576);
    k_cast<<<dim3(1024), dim3(256), 0, stream>>>(Wout, Wout16, 262144);
    k_tr  <<<dim3(32, 2), dim3(256), 0, stream>>>(Wout, WoutT);
    k_x0  <<<dim3(256), dim3(256), 0, stream>>>(tgt, x0);
    k_bias<<<dim3(32), dim3(256), 0, stream>>>(bih, bhh, Wih, bout, b0, bp);
    k_wcomb2<<<dim3(16, 64), dim3(512), 0, stream>>>(Wih16, WoutT, Whh, Wc);

    // step 0: gates = x0 @ W_ih^T + (b_ih+b_hh)  -> h^1 in slot 0
    k_step<<<dim3(256), dim3(512), 0, stream>>>(x0, 128, 128, Wih16, 128, b0, Cst, Hbuf);
    // steps 1..127: gates = h @ W'^T + b'
    for (int s = 1; s < 128; ++s) {
        if ((s % depth) == 0)
            k_out<<<dim3(depth * 4), dim3(512), 0, stream>>>(Hbuf, Wout16, bout, out, s - depth);
        k_step<<<dim3(256), dim3(512), 0, stream>>>(
            Hbuf + (size_t)((s - 1) % depth) * slotsz, 2048, 2048, Wc, 2048, bp,
            Cst, Hbuf + (size_t)(s % depth) * slotsz);
    }
    k_out<<<dim3(depth * 4), dim3(512), 0, stream>>>(Hbuf, Wout16, bout, out, 128 - depth);
}

// Round 5
// 8226.839 us; speedup vs baseline: 1.4689x; 1.4689x over previous
//
#include <hip/hip_runtime.h>
#include <hip/hip_fp16.h>

typedef _Float16 f16;
typedef __attribute__((ext_vector_type(4))) _Float16 f16x4;
typedef __attribute__((ext_vector_type(8))) _Float16 f16x8;
typedef __attribute__((ext_vector_type(4))) float f32x4;

#define SWZ(r) ((((r)&3) ^ (((r)>>2)&3)))

// persistent-kernel LDS: staging dbuf 2*(A 32KB + B 32KB) = 128KB,
// reduction buffer 4 ks * 128 n * 68 m-pad * 4B = 136KB; union -> 139264 B
#define PERS_LDS 139264
#define RSTRIDE 68
#define RKS (128 * RSTRIDE)

// ---------------------------------------------------------------------------
// Persistent LSTM decoder: all 128 steps + output projections in ONE kernel.
// Grid 256 (1 block/CU, forced by LDS), 512 threads (8 waves = ms2 x ks4).
// Block tile: 128 batch x 128 gate-rows (= 4 gates x 32 hid, ng-sliced),
// K split 4-way across ks-waves, reduced via LDS; cell fused in-register.
// B row map: tile row rb -> nbase + (rb>>5)*nstride + (rb&31)
//   (nstride=2048: gate-major weights; nstride=32: identity for Wout).
// Weights XCD-pinned: each XCD's 8 ng-slices = 4MB W' = its L2, hot for all
// 128 steps. Grid sync: counter barrier (residency forced by LDS).
// ---------------------------------------------------------------------------
__global__ __launch_bounds__(512, 2) void k_persist(
    const f16* __restrict__ x0, const f16* __restrict__ Wih16,
    const f16* __restrict__ Wc, const f16* __restrict__ WoutG,
    const float* __restrict__ b0, const float* __restrict__ bp,
    const float* __restrict__ bout,
    float* __restrict__ Cst, f16* __restrict__ Hbuf,
    float* __restrict__ out, unsigned* __restrict__ cnt, int depth)
{
    extern __shared__ char ldsraw[];
    f16*   stg = (f16*)ldsraw;    // A: [buf][ks-chunk 4][4096]; B at +32768 f16
    float* red = (float*)ldsraw;  // [ks 4][n 128][m 64 pad 68]

    const int bid  = blockIdx.x;
    const int ng   = (bid & 7) * 8 + ((bid >> 3) & 7);  // 0..63, xcd-pinned
    const int mg   = bid >> 6;                          // batch-group 0..3
    const int tid  = threadIdx.x;
    const int w    = tid >> 6, lane = tid & 63;
    const int l15  = lane & 15, quad = lane >> 4;
    const int ms   = w & 1, ks = w >> 1;
    const size_t slotsz = (size_t)512 * 2048;

    // staging: thread -> (row 0..127, k-quad) of each 8KB chunk
    const int srow = w * 16 + (lane >> 2);
    const int skq  = (lane & 3) ^ SWZ(srow);

    // fragment LDS offsets (within a 4096-f16 chunk)
    int offA[4], offB[8];
    #pragma unroll
    for (int mt = 0; mt < 4; ++mt) {
        int r = ms * 64 + mt * 16 + l15;
        offA[mt] = (r * 4 + (quad ^ SWZ(r))) * 8;
    }
    #pragma unroll
    for (int nt = 0; nt < 8; ++nt) {
        int r = nt * 16 + l15;
        offB[nt] = (r * 4 + (quad ^ SWZ(r))) * 8;
    }

    unsigned nsync = 0;
    auto gbar = [&]() {
        __syncthreads();
        ++nsync;
        if (tid == 0) {
            __threadfence();   // release: wbl2 flushes all block stores in L2
            __hip_atomic_fetch_add(cnt, 1u, __ATOMIC_RELEASE, __HIP_MEMORY_SCOPE_AGENT);
            const unsigned tgt = 256u * nsync;
            int guard = 0;
            while (__hip_atomic_load(cnt, __ATOMIC_ACQUIRE, __HIP_MEMORY_SCOPE_AGENT) < tgt
                   && ++guard < 5000000) __builtin_amdgcn_s_sleep(2);
            __threadfence();   // acquire: inv L1/L2 so whole CU refetches
        }
        __syncthreads();
    };

    auto stage = [&](const f16* At, int lda, const f16* Bt, int ldb,
                     int nbase, int nstride, int kqlen, int mi, int buf) {
        const int ko = mi * 32 + skq * 8;
        const f16* a = At + (size_t)srow * lda + ko;
        const int brow = nbase + (srow >> 5) * nstride + (srow & 31);
        const f16* b = Bt + (size_t)brow * ldb + ko;
        f16* da = stg + buf * 16384 + w * 512;
        f16* db = stg + 32768 + buf * 16384 + w * 512;
        #pragma unroll
        for (int q = 0; q < 4; ++q) {
            __builtin_amdgcn_global_load_lds(
                (const __attribute__((address_space(1))) void*)(a + q * kqlen),
                (__attribute__((address_space(3))) void*)(da + q * 4096), 16, 0, 0);
            __builtin_amdgcn_global_load_lds(
                (const __attribute__((address_space(1))) void*)(b + q * kqlen),
                (__attribute__((address_space(3))) void*)(db + q * 4096), 16, 0, 0);
        }
    };

    f32x4 acc[4][8];
    auto gemm = [&](const f16* At, int lda, const f16* Bt, int ldb,
                    int nbase, int nstride, int K) {
        #pragma unroll
        for (int mt = 0; mt < 4; ++mt)
            #pragma unroll
            for (int nt = 0; nt < 8; ++nt)
                acc[mt][nt] = (f32x4){0.f, 0.f, 0.f, 0.f};
        const int kqlen = K >> 2, KM = kqlen >> 5;
        stage(At, lda, Bt, ldb, nbase, nstride, kqlen, 0, 0);
        for (int mi = 0; mi < KM; ++mi) {
            __syncthreads();  // buf (mi&1) ready (vmcnt drained per wave)
            if (mi + 1 < KM)
                stage(At, lda, Bt, ldb, nbase, nstride, kqlen, mi + 1, (mi + 1) & 1);
            const f16* base = stg + (mi & 1) * 16384 + ks * 4096;
            f16x8 af[4], bf[8];
            #pragma unroll
            for (int mt = 0; mt < 4; ++mt) af[mt] = *(const f16x8*)(base + offA[mt]);
            #pragma unroll
            for (int nt = 0; nt < 8; ++nt) bf[nt] = *(const f16x8*)(base + 32768 + offB[nt]);
            #pragma unroll
            for (int mt = 0; mt < 4; ++mt)
                #pragma unroll
                for (int nt = 0; nt < 8; ++nt)
                    acc[mt][nt] = __builtin_amdgcn_mfma_f32_16x16x32_f16(
                        af[mt], bf[nt], acc[mt][nt], 0, 0, 0);
        }
        __syncthreads();  // before LDS reuse as red
    };

    auto dump = [&](int p) {
        if (ms == p) {
            #pragma unroll
            for (int nt = 0; nt < 8; ++nt) {
                float* dst = red + ks * RKS + (nt * 16 + l15) * RSTRIDE + quad * 4;
                #pragma unroll
                for (int mt = 0; mt < 4; ++mt)
                    *(f32x4*)(dst + mt * 16) = acc[mt][nt];
            }
        }
        __syncthreads();
    };

    auto cell = [&](int p, int s, f16* hdst) {
        const int mloc = tid >> 3, hq = (tid & 7) * 4;
        const int m = mg * 128 + p * 64 + mloc;
        const int hid = ng * 32 + hq;
        const float* bias = (s == 0) ? b0 : bp;
        const size_t cidx = (size_t)m * 2048 + hid;
        f32x4 cold = *(const f32x4*)(Cst + cidx);
        f32x4 gv[4];
        #pragma unroll
        for (int g = 0; g < 4; ++g) {
            f32x4 v = *(const f32x4*)(bias + g * 2048 + hid);
            #pragma unroll
            for (int kk = 0; kk < 4; ++kk) {
                const float* rp = red + kk * RKS + (g * 32 + hq) * RSTRIDE + mloc;
                v[0] += rp[0]; v[1] += rp[RSTRIDE];
                v[2] += rp[2 * RSTRIDE]; v[3] += rp[3 * RSTRIDE];
            }
            gv[g] = v;
        }
        f32x4 cnew; f16x4 hv;
        #pragma unroll
        for (int u = 0; u < 4; ++u) {
            float si = 1.f / (1.f + __expf(-gv[0][u]));
            float sf = 1.f / (1.f + __expf(-gv[1][u]));
            float tg = tanhf(gv[2][u]);
            float so = 1.f / (1.f + __expf(-gv[3][u]));
            float c = sf * cold[u] + si * tg;
            cnew[u] = c;
            hv[u] = (f16)(so * tanhf(c));
        }
        *(f32x4*)(Cst + cidx) = cnew;
        *(f16x4*)(hdst + cidx) = hv;
        __syncthreads();
    };

    auto burst = [&](int t0, int nslots) {
        const int tiles = nslots * 4;
        for (int tt = bid; tt < tiles; tt += 256) {
            const int slot = tt >> 2, mq = tt & 3;
            const f16* At = Hbuf + slot * slotsz + (size_t)mq * 128 * 2048;
            gemm(At, 2048, WoutG, 2048, 0, 32, 2048);  // identity row map
            for (int p = 0; p < 2; ++p) {
                dump(p);
                const int mloc = tid >> 3, nq = (tid & 7) * 16;
                const int b = mq * 128 + p * 64 + mloc;
                float* op = out + (size_t)b * 16384 + (t0 + slot) * 128 + nq;
                #pragma unroll
                for (int v4 = 0; v4 < 4; ++v4) {
                    f32x4 v = *(const f32x4*)(bout + nq + v4 * 4);
                    #pragma unroll
                    for (int kk = 0; kk < 4; ++kk) {
                        const float* rp = red + kk * RKS + (nq + v4 * 4) * RSTRIDE + mloc;
                        v[0] += rp[0]; v[1] += rp[RSTRIDE];
                        v[2] += rp[2 * RSTRIDE]; v[3] += rp[3 * RSTRIDE];
                    }
                    *(f32x4*)(op + v4 * 4) = v;
                }
                __syncthreads();
            }
        }
        gbar();
    };

    for (int s = 0; s < 128; ++s) {
        if (s > 0 && (s % depth) == 0) burst(s - depth, depth);
        const f16* At; int lda, K; const f16* Bt; int ldb;
        if (s == 0) { At = x0 + (size_t)mg * 128 * 128; lda = 128; K = 128;
                      Bt = Wih16; ldb = 128; }
        else { At = Hbuf + (size_t)((s - 1) % depth) * slotsz + (size_t)mg * 128 * 2048;
               lda = 2048; K = 2048; Bt = Wc; ldb = 2048; }
        gemm(At, lda, Bt, ldb, ng * 32, 2048, K);
        f16* hdst = Hbuf + (size_t)(s % depth) * slotsz;
        dump(0); cell(0, s, hdst);
        dump(1); cell(1, s, hdst);
        gbar();
    }
    burst(128 - depth, depth);
}

// ---------------- prep kernels (proven in rounds 1-2) -----------------------

__device__ __forceinline__ void gemm128(
    const f16* __restrict__ A, int lda,
    const f16* __restrict__ Bm, int ldb,
    int K, int bm0, int nbase, int strideG,
    f16* As, f16* Bs, f32x4 acc[4][4])
{
    const int tid  = threadIdx.x;
    const int wave = tid >> 6;
    const int lane = tid & 63;
    const int l15  = lane & 15;
    const int quad = lane >> 4;
    const int mhalf = wave & 1, hhalf = wave >> 1;

    #pragma unroll
    for (int mt = 0; mt < 4; ++mt)
      #pragma unroll
      for (int nt = 0; nt < 4; ++nt)
        acc[mt][nt] = (f32x4){0.f, 0.f, 0.f, 0.f};

    const int c0 = tid, c1 = tid + 256;
    const int r0 = c0 >> 2, r1 = c1 >> 2;
    const int kq0 = (c0 & 3) ^ SWZ(r0);
    const int kq1 = (c1 & 3) ^ SWZ(r1);
    const f16* gA0 = A + (size_t)(bm0 + r0) * lda + kq0 * 8;
    const f16* gA1 = A + (size_t)(bm0 + r1) * lda + kq1 * 8;
    const int br0 = nbase + (r0 >> 5) * strideG + ((r0 >> 4) & 1) * 16 + (r0 & 15);
    const int br1 = nbase + (r1 >> 5) * strideG + ((r1 >> 4) & 1) * 16 + (r1 & 15);
    const f16* gB0 = Bm + (size_t)br0 * ldb + kq0 * 8;
    const f16* gB1 = Bm + (size_t)br1 * ldb + kq1 * 8;

    f16* ldsA0 = As + wave * 512;
    f16* ldsA1 = As + 2048 + wave * 512;
    f16* ldsB0 = Bs + wave * 512;
    f16* ldsB1 = Bs + 2048 + wave * 512;

    int offA[4], offB[4];
    const int sw = SWZ(l15);
    #pragma unroll
    for (int mt = 0; mt < 4; ++mt) {
        int r = mhalf * 64 + mt * 16 + l15;
        offA[mt] = (r * 4 + (quad ^ sw)) * 8;
    }
    #pragma unroll
    for (int nt = 0; nt < 4; ++nt) {
        int r = nt * 32 + hhalf * 16 + l15;
        offB[nt] = (r * 4 + (quad ^ sw)) * 8;
    }

    for (int k0 = 0; k0 < K; k0 += 32) {
        __builtin_amdgcn_global_load_lds(
            (const __attribute__((address_space(1))) void*)(gA0 + k0),
            (__attribute__((address_space(3))) void*)ldsA0, 16, 0, 0);
        __builtin_amdgcn_global_load_lds(
            (const __attribute__((address_space(1))) void*)(gA1 + k0),
            (__attribute__((address_space(3))) void*)ldsA1, 16, 0, 0);
        __builtin_amdgcn_global_load_lds(
            (const __attribute__((address_space(1))) void*)(gB0 + k0),
            (__attribute__((address_space(3))) void*)ldsB0, 16, 0, 0);
        __builtin_amdgcn_global_load_lds(
            (const __attribute__((address_space(1))) void*)(gB1 + k0),
            (__attribute__((address_space(3))) void*)ldsB1, 16, 0, 0);
        __syncthreads();
        f16x8 af[4], bf[4];
        #pragma unroll
        for (int mt = 0; mt < 4; ++mt) af[mt] = *(const f16x8*)(As + offA[mt]);
        #pragma unroll
        for (int nt = 0; nt < 4; ++nt) bf[nt] = *(const f16x8*)(Bs + offB[nt]);
        #pragma unroll
        for (int mt = 0; mt < 4; ++mt)
          #pragma unroll
          for (int nt = 0; nt < 4; ++nt)
            acc[mt][nt] = __builtin_amdgcn_mfma_f32_16x16x32_f16(
                af[mt], bf[nt], acc[mt][nt], 0, 0, 0);
        __syncthreads();
    }
}

// W'[r,k] = W_hh[r,k] + sum_d W_ih[r,d]*W_out[d,k]
__global__ __launch_bounds__(256, 1) void k_wcomb2(
    const f16* __restrict__ Wih16, const f16* __restrict__ WoutT,
    const float* __restrict__ Whh, f16* __restrict__ Wcout)
{
    __shared__ alignas(16) f16 As[4096];
    __shared__ alignas(16) f16 Bs[4096];
    const int n0  = blockIdx.x * 128;
    const int bm0 = blockIdx.y * 128;
    f32x4 acc[4][4];
    gemm128(Wih16, 128, WoutT, 128, 128, bm0, n0, 32, As, Bs, acc);
    const int lane = threadIdx.x & 63;
    const int wave = threadIdx.x >> 6;
    const int l15 = lane & 15, quad = lane >> 4;
    const int mhalf = wave & 1, hhalf = wave >> 1;
    #pragma unroll
    for (int nt = 0; nt < 4; ++nt) {
      const int col = n0 + nt * 32 + hhalf * 16 + l15;
      #pragma unroll
      for (int mt = 0; mt < 4; ++mt) {
        #pragma unroll
        for (int reg = 0; reg < 4; ++reg) {
          const int row = bm0 + mhalf * 64 + mt * 16 + quad * 4 + reg;
          const size_t idx = (size_t)row * 2048 + col;
          Wcout[idx] = (f16)(acc[mt][nt][reg] + Whh[idx]);
        }
      }
    }
}

__global__ void k_cast(const float* __restrict__ s, f16* __restrict__ d, int n)
{
    int i = blockIdx.x * 256 + threadIdx.x;
    if (i < n) d[i] = (f16)s[i];
}

// WoutT[k,d] = Wout[d,k]  (fp32 [128 x 2048] -> f16 [2048 x 128])
__global__ __launch_bounds__(256) void k_tr(const float* __restrict__ Wout,
                                            f16* __restrict__ WoutT)
{
    __shared__ float T[64][65];
    const int k0 = blockIdx.x * 64;
    const int d0 = blockIdx.y * 64;
    const int t = threadIdx.x;
    const int r = t >> 2, cq = t & 3;
    #pragma unroll
    for (int jj = 0; jj < 4; ++jj) {
        const float* p = Wout + (size_t)(d0 + r) * 2048 + k0 + cq * 16 + jj * 4;
        T[r][cq * 16 + jj * 4 + 0] = p[0];
        T[r][cq * 16 + jj * 4 + 1] = p[1];
        T[r][cq * 16 + jj * 4 + 2] = p[2];
        T[r][cq * 16 + jj * 4 + 3] = p[3];
    }
    __syncthreads();
    f16 tmp[16];
    #pragma unroll
    for (int jj = 0; jj < 16; ++jj) tmp[jj] = (f16)T[cq * 16 + jj][r];
    #pragma unroll
    for (int jj = 0; jj < 16; ++jj)
        WoutT[(size_t)(k0 + r) * 128 + d0 + cq * 16 + jj] = tmp[jj];
}

__global__ void k_x0(const float* __restrict__ tgt, f16* __restrict__ x0)
{
    int i = blockIdx.x * 256 + threadIdx.x;
    int b = i >> 7, d = i & 127;
    x0[i] = (f16)tgt[(size_t)b * 16384 + d];
}

__global__ void k_bias(const float* __restrict__ bih, const float* __restrict__ bhh,
                       const float* __restrict__ Wih, const float* __restrict__ bout,
                       float* __restrict__ b0, float* __restrict__ bp)
{
    int r = blockIdx.x * 256 + threadIdx.x;
    if (r >= 8192) return;
    float s = bih[r] + bhh[r];
    float a = 0.f;
    for (int d = 0; d < 128; ++d) a += Wih[(size_t)r * 128 + d] * bout[d];
    b0[r] = s;
    bp[r] = s + a;
}

// ---------------------------------------------------------------------------

extern "C" void kernel_launch(void* const* d_in, const int* in_sizes, int n_in,
                              void* d_out, int out_size, void* d_ws, size_t ws_size,
                              hipStream_t stream)
{
    const float* tgt  = (const float*)d_in[0];
    const float* Wih  = (const float*)d_in[1];
    const float* Whh  = (const float*)d_in[2];
    const float* bih  = (const float*)d_in[3];
    const float* bhh  = (const float*)d_in[4];
    const float* Wout = (const float*)d_in[5];
    const float* bout = (const float*)d_in[6];
    float* out = (float*)d_out;

    char* ws = (char*)d_ws;
    size_t off = 0;
    auto alloc = [&](size_t bytes) -> void* {
        void* p = ws + off;
        off += (bytes + 255) & ~(size_t)255;
        return p;
    };
    f16*   Wc     = (f16*)alloc((size_t)8192 * 2048 * 2);
    f16*   Wih16  = (f16*)alloc((size_t)8192 * 128 * 2);
    f16*   WoutG  = (f16*)alloc((size_t)128 * 2048 * 2);  // plain f16 cast
    f16*   WoutT  = (f16*)alloc((size_t)2048 * 128 * 2);
    f16*   x0     = (f16*)alloc((size_t)512 * 128 * 2);
    float* b0     = (float*)alloc(8192 * 4);
    float* bp     = (float*)alloc(8192 * 4);
    float* Cst    = (float*)alloc((size_t)512 * 2048 * 4);
    unsigned* cnt = (unsigned*)alloc(256);

    const size_t slotsz = (size_t)512 * 2048;
    int depth = 0;
    const int cands[7] = {128, 64, 32, 16, 8, 4, 2};
    for (int i = 0; i < 7; ++i)
        if (off + (size_t)cands[i] * slotsz * 2 <= ws_size) { depth = cands[i]; break; }
    if (depth == 0) return;
    f16* Hbuf = (f16*)alloc((size_t)depth * slotsz * 2);

    hipMemsetAsync(Cst, 0, (size_t)512 * 2048 * 4, stream);
    hipMemsetAsync(cnt, 0, 256, stream);
    k_cast <<<dim3(4096), dim3(256), 0, stream>>>(Wih, Wih16, 1048576);
    k_cast <<<dim3(1024), dim3(256), 0, stream>>>(Wout, WoutG, 262144);
    k_tr   <<<dim3(32, 2), dim3(256), 0, stream>>>(Wout, WoutT);
    k_x0   <<<dim3(256), dim3(256), 0, stream>>>(tgt, x0);
    k_bias <<<dim3(32), dim3(256), 0, stream>>>(bih, bhh, Wih, bout, b0, bp);
    k_wcomb2<<<dim3(16, 64), dim3(256), 0, stream>>>(Wih16, WoutT, Whh, Wc);

    hipFuncSetAttribute((const void*)k_persist,
                        hipFuncAttributeMaxDynamicSharedMemorySize, PERS_LDS);
    k_persist<<<dim3(256), dim3(512), PERS_LDS, stream>>>(
        x0, Wih16, Wc, WoutG, b0, bp, bout, Cst, Hbuf, out, cnt, depth);
}